// Round 1
// 174.579 us; speedup vs baseline: 1.0346x; 1.0346x over previous
//
#include <hip/hip_runtime.h>
#include <hip/hip_bf16.h>

typedef float v4 __attribute__((ext_vector_type(4)));
typedef float f32x4 __attribute__((ext_vector_type(4)));
typedef short s8 __attribute__((ext_vector_type(8)));
typedef short s4 __attribute__((ext_vector_type(4)));

__device__ __forceinline__ short f2b(float x) {
  return __builtin_bit_cast(short, __float2bfloat16(x));
}
__device__ __forceinline__ float b2f(short s) {
  return __bfloat162float(__builtin_bit_cast(__hip_bfloat16, s));
}

// Dims: B=64 M=30 N=10 AGENT=256 EGO=256 LAT=32 NA=11 NP=4 PAY=1024 FUT=240

// ---------------------------------------------------------------------------
// K-pre: fused weight packing (blocks 0..1005) + ego MLP (blocks 1006..1485,
// 4 bm per block). Pool layout (short-element offsets), frags [kt][nt][lane][8]:
//   PC0 @0        Wp1 cond rows (virt K1520 pad 1536), 48kt x 32nt   786432
//   PC1 @786432   Wg1 cond rows (K1280),               40kt x 32nt   655360
//   PE0 @1441792  Wp1 ego rows 256..511 (K256),         8kt x 32nt   131072
//   PE1 @1572864  Wg1 ego rows (K256),                  8kt x 32nt   131072
//   P2p @1703936  Wp2 (512x256),                       16kt x 16nt   131072
//   G2p @1835008  Wg2,                                 16kt x 16nt   131072
//   G3p @1966080  Wg3 (256x240),                        8kt x 15nt    61440
//   G1p @2027520  Wg1 rows 1536..1567 (K=32),           1kt x 32nt    16384
//   ZPp @2043904  [Wmu|Wlv] (256x64),                   8kt x  4nt    16384
// ---------------------------------------------------------------------------
__global__ __launch_bounds__(256) void k_pre(
    const float* __restrict__ Wp1, const float* __restrict__ Wg1,
    const float* __restrict__ Wp2, const float* __restrict__ Wg2,
    const float* __restrict__ Wg3, const float* __restrict__ Wmu,
    const float* __restrict__ Wlv, short* __restrict__ pool,
    const float* __restrict__ x, const float* __restrict__ W1,
    const float* __restrict__ b1, const float* __restrict__ W2,
    const float* __restrict__ b2, float* __restrict__ ego) {
  const int t = threadIdx.x;
  if (blockIdx.x >= 1006) {
    // ---- ego MLP: 4 bm rows per block, vectorized LDS reads ----
    __shared__ __align__(16) float xls[1920];    // 4 x 480
    __shared__ float hpart[2][4][128];
    __shared__ float hbar[4][128];
    const int bm0 = (blockIdx.x - 1006) * 4;
    const float* xp = x + bm0 * 480;
#pragma unroll
    for (int i = 0; i < 2; ++i) {
      int idx = t + i * 256;  // 480 v4 items total
      if (idx < 480) *(v4*)&xls[idx * 4] = *(const v4*)&xp[idx * 4];
    }
    __syncthreads();
    {
      const int hid = t & 127, th = t >> 7;
      float w0 = W1[0 * 128 + hid], w1 = W1[1 * 128 + hid];
      float w2 = W1[2 * 128 + hid], w3 = W1[3 * 128 + hid];
      float w4 = W1[4 * 128 + hid], w5 = W1[5 * 128 + hid];
      float bb = b1[hid];
#pragma unroll 1
      for (int bm = 0; bm < 4; ++bm) {
        const float* base = &xls[bm * 480 + th * 240];
        float acc = 0.f;
#pragma unroll 4
        for (int tt = 0; tt < 40; tt += 2) {
          v4 a = *(const v4*)(base + tt * 6);
          v4 b = *(const v4*)(base + tt * 6 + 4);
          v4 c = *(const v4*)(base + tt * 6 + 8);
          float h0 = bb;
          h0 = fmaf(a[0], w0, h0); h0 = fmaf(a[1], w1, h0);
          h0 = fmaf(a[2], w2, h0); h0 = fmaf(a[3], w3, h0);
          h0 = fmaf(b[0], w4, h0); h0 = fmaf(b[1], w5, h0);
          float h1 = bb;
          h1 = fmaf(b[2], w0, h1); h1 = fmaf(b[3], w1, h1);
          h1 = fmaf(c[0], w2, h1); h1 = fmaf(c[1], w3, h1);
          h1 = fmaf(c[2], w4, h1); h1 = fmaf(c[3], w5, h1);
          acc += fmaxf(h0, 0.f) + fmaxf(h1, 0.f);
        }
        hpart[th][bm][hid] = acc;
      }
    }
    __syncthreads();
    if (t < 128) {
#pragma unroll
      for (int bm = 0; bm < 4; ++bm)
        hbar[bm][t] = (hpart[0][bm][t] + hpart[1][bm][t]) * (1.0f / 80.0f);
    }
    __syncthreads();
    {
      float acc0 = b2[t], acc1 = acc0, acc2 = acc0, acc3 = acc0;
#pragma unroll 8
      for (int j = 0; j < 128; ++j) {
        float w = W2[j * 256 + t];
        acc0 = fmaf(hbar[0][j], w, acc0);
        acc1 = fmaf(hbar[1][j], w, acc1);
        acc2 = fmaf(hbar[2][j], w, acc2);
        acc3 = fmaf(hbar[3][j], w, acc3);
      }
      ego[(bm0 + 0) * 256 + t] = acc0;
      ego[(bm0 + 1) * 256 + t] = acc1;
      ego[(bm0 + 2) * 256 + t] = acc2;
      ego[(bm0 + 3) * 256 + t] = acc3;
    }
    return;
  }
  int idx = blockIdx.x * 256 + t;
  const float* W; short* O; int NT, N, rel, mode, Kv;
  if (idx < 98304)       { W = Wp1;            O = pool;           NT = 32; N = 512; rel = idx;          mode = 0; Kv = 1520; }
  else if (idx < 180224) { W = Wg1;            O = pool + 786432;  NT = 32; N = 512; rel = idx - 98304;  mode = 0; Kv = 1280; }
  else if (idx < 196608) { W = Wp1 + 256*512;  O = pool + 1441792; NT = 32; N = 512; rel = idx - 180224; mode = 1; Kv = 256; }
  else if (idx < 212992) { W = Wg1 + 256*512;  O = pool + 1572864; NT = 32; N = 512; rel = idx - 196608; mode = 1; Kv = 256; }
  else if (idx < 229376) { W = Wp2;            O = pool + 1703936; NT = 16; N = 256; rel = idx - 212992; mode = 1; Kv = 512; }
  else if (idx < 245760) { W = Wg2;            O = pool + 1835008; NT = 16; N = 256; rel = idx - 229376; mode = 1; Kv = 512; }
  else if (idx < 253440) { W = Wg3;            O = pool + 1966080; NT = 15; N = 240; rel = idx - 245760; mode = 1; Kv = 256; }
  else if (idx < 255488) { W = Wg1 + 1536*512; O = pool + 2027520; NT = 32; N = 512; rel = idx - 253440; mode = 1; Kv = 32; }
  else if (idx < 257536) { W = Wmu;            O = pool + 2043904; NT = 4;  N = 64;  rel = idx - 255488; mode = 2; Kv = 256; }
  else return;
  int lane = rel & 63, g = rel >> 6;
  int nt = g % NT, kt = g / NT;
  int k0 = kt * 32 + (lane >> 4) * 8;
  int n = nt * 16 + (lane & 15);
  s8 pk;
#pragma unroll
  for (int j = 0; j < 8; ++j) {
    int vk = k0 + j;
    float v = 0.f;
    if (vk < Kv) {
      if (mode == 2) v = (n < 32) ? Wmu[vk * 32 + n] : Wlv[vk * 32 + (n - 32)];
      else {
        int wrow = (mode == 0 && vk >= 256) ? vk + 256 : vk;
        v = W[wrow * N + n];
      }
    }
    pk[j] = f2b(v);
  }
  *(s8*)&O[rel * 8] = pk;
}

// ---------------------------------------------------------------------------
// K-condE: merged-pair A/E GEMMs, 256 thr, col-quarter split.
// grid (120, 2, 4): grp0 tiles 0..39 (cond), grp1 tiles 0..119 (ego).
// ---------------------------------------------------------------------------
__global__ __launch_bounds__(256, 4) void k_condE(
    const float* __restrict__ enc, const float* __restrict__ gtf,
    const int* __restrict__ nidx, const float* __restrict__ ego,
    const short* __restrict__ pool, short* __restrict__ Apb,
    short* __restrict__ Agb, short* __restrict__ Epb,
    short* __restrict__ Egb) {
  __shared__ __align__(16) short xs[16 * 1560];
  const int grp = blockIdx.y, tile = blockIdx.x, quarter = blockIdx.z;
  if (grp == 0 && tile >= 40) return;
  const int row0 = tile * 16;
  const int t = threadIdx.x;
  const int wave = t >> 6, lane = t & 63;
  const int m = lane & 15, quad = lane >> 4;
  const int ntg = quarter * 8 + wave * 2;

  if (grp == 0) {
    for (int i = t; i < 3072; i += 256) {
      int s = i / 192, kk = (i - s * 192) * 8;
      int r = row0 + s;
      s8 pk;
      if (kk >= 1520) {
#pragma unroll
        for (int j = 0; j < 8; ++j) pk[j] = 0;
      } else {
        int bb = r / 10, n = r - bb * 10;
        const float* src;
        if (kk < 256) src = enc + (bb * 11 + 1 + n) * 256 + kk;
        else if (kk < 1280) {
          int jj = kk - 256; int p = jj >> 8, cc = jj & 255;
          int a = nidx[(bb * 10 + n) * 4 + p];
          src = enc + (bb * 11 + a) * 256 + cc;
        } else src = gtf + (bb * 10 + n) * 240 + (kk - 1280);
        v4 a = *(const v4*)src;
        v4 b = *(const v4*)(src + 4);
#pragma unroll
        for (int j = 0; j < 4; ++j) { pk[j] = f2b(a[j]); pk[4 + j] = f2b(b[j]); }
      }
      *(s8*)&xs[s * 1560 + kk] = pk;
    }
    __syncthreads();
    const short* PC1 = pool + 786432;
    f32x4 aP[2] = {{0}, {0}}, aG[2] = {{0}, {0}};
    s8 c0[2], c1[2];
#pragma unroll
    for (int i = 0; i < 2; ++i) {
      c0[i] = *(const s8*)&pool[((ntg + i) * 64 + lane) * 8];
      c1[i] = *(const s8*)&PC1[((ntg + i) * 64 + lane) * 8];
    }
#pragma unroll 2
    for (int kt = 0; kt < 48; ++kt) {
      s8 n0[2], n1[2];
      if (kt < 47) {
#pragma unroll
        for (int i = 0; i < 2; ++i)
          n0[i] = *(const s8*)&pool[(((kt + 1) * 32 + ntg + i) * 64 + lane) * 8];
        if (kt + 1 < 40) {
#pragma unroll
          for (int i = 0; i < 2; ++i)
            n1[i] = *(const s8*)&PC1[(((kt + 1) * 32 + ntg + i) * 64 + lane) * 8];
        }
      }
      s8 a = *(const s8*)&xs[m * 1560 + kt * 32 + quad * 8];
#pragma unroll
      for (int i = 0; i < 2; ++i)
        aP[i] = __builtin_amdgcn_mfma_f32_16x16x32_bf16(a, c0[i], aP[i], 0, 0, 0);
      if (kt < 40) {
#pragma unroll
        for (int i = 0; i < 2; ++i)
          aG[i] = __builtin_amdgcn_mfma_f32_16x16x32_bf16(a, c1[i], aG[i], 0, 0, 0);
      }
      c0[0] = n0[0]; c0[1] = n0[1]; c1[0] = n1[0]; c1[1] = n1[1];
    }
#pragma unroll
    for (int i = 0; i < 2; ++i) {
      int col = (ntg + i) * 16 + m;
#pragma unroll
      for (int r = 0; r < 4; ++r) {
        int row = row0 + quad * 4 + r;
        Apb[row * 512 + col] = f2b(aP[i][r]);
        Agb[row * 512 + col] = f2b(aG[i][r]);
      }
    }
  } else {
    for (int i = t; i < 512; i += 256) {
      int s = i >> 5, kk = (i & 31) * 8;
      const float* src = ego + (row0 + s) * 256 + kk;
      v4 a = *(const v4*)src;
      v4 b = *(const v4*)(src + 4);
      s8 pk;
#pragma unroll
      for (int j = 0; j < 4; ++j) { pk[j] = f2b(a[j]); pk[4 + j] = f2b(b[j]); }
      *(s8*)&xs[s * 1560 + kk] = pk;
    }
    __syncthreads();
    const short* PE0 = pool + 1441792;
    const short* PE1 = pool + 1572864;
    f32x4 aP[2] = {{0}, {0}}, aG[2] = {{0}, {0}};
    s8 c0[2], c1[2];
#pragma unroll
    for (int i = 0; i < 2; ++i) {
      c0[i] = *(const s8*)&PE0[((ntg + i) * 64 + lane) * 8];
      c1[i] = *(const s8*)&PE1[((ntg + i) * 64 + lane) * 8];
    }
#pragma unroll 2
    for (int kt = 0; kt < 8; ++kt) {
      s8 n0[2], n1[2];
      if (kt < 7) {
#pragma unroll
        for (int i = 0; i < 2; ++i) {
          n0[i] = *(const s8*)&PE0[(((kt + 1) * 32 + ntg + i) * 64 + lane) * 8];
          n1[i] = *(const s8*)&PE1[(((kt + 1) * 32 + ntg + i) * 64 + lane) * 8];
        }
      }
      s8 a = *(const s8*)&xs[m * 1560 + kt * 32 + quad * 8];
#pragma unroll
      for (int i = 0; i < 2; ++i) {
        aP[i] = __builtin_amdgcn_mfma_f32_16x16x32_bf16(a, c0[i], aP[i], 0, 0, 0);
        aG[i] = __builtin_amdgcn_mfma_f32_16x16x32_bf16(a, c1[i], aG[i], 0, 0, 0);
      }
      c0[0] = n0[0]; c0[1] = n0[1]; c1[0] = n1[0]; c1[1] = n1[1];
    }
#pragma unroll
    for (int i = 0; i < 2; ++i) {
      int col = (ntg + i) * 16 + m;
#pragma unroll
      for (int r = 0; r < 4; ++r) {
        int row = row0 + quad * 4 + r;
        Epb[row * 512 + col] = f2b(aP[i][r]);
        Egb[row * 512 + col] = f2b(aG[i][r]);
      }
    }
  }
}

// ---------------------------------------------------------------------------
// K-mega: mixed grid for exact 2-blocks/CU balance:
//   blocks 0..175   -> 48 samples (NMI=3 tiles), base = blk*48
//   blocks 176..511 -> 32 samples (NMI=2 tiles), base = 8448 + (blk-176)*32
// 512 blocks pair (b, b+256) on the same CU under round-robin dispatch, so
// every CU hosts one heavy + one light block (80 samples-worth vs the old
// worst case of 96). Zero MFMA padding (48=3x16, 32=2x16). LDS layout kept at
// the 48-row size (54528 B -> 2 blocks/CU):
//   h1h [48][264] bf16 (25344)  half-K hp1/sumG/hg1; zf overlay [2*ns][33] f32
//   h2c [48][264] bf16 (25344)  hp2, reused as hg2
//   zb  [48][40]  bf16 ( 3840)
// ---------------------------------------------------------------------------
template <int NMI>
__device__ __forceinline__ void mega_body(
    const int base,
    const short* __restrict__ Apb, const short* __restrict__ Agb,
    const short* __restrict__ Epb, const short* __restrict__ Egb,
    const float* __restrict__ bp1, const float* __restrict__ bg1,
    const float* __restrict__ bp2, const float* __restrict__ bmu,
    const float* __restrict__ blv, const float* __restrict__ eps,
    const float* __restrict__ bg2, const float* __restrict__ bg3,
    const short* __restrict__ P2p, const short* __restrict__ G2p,
    const short* __restrict__ G3p, const short* __restrict__ G1p,
    const short* __restrict__ ZPp, float* __restrict__ out,
    short* h1h, short* h2c, short* zb, float* zf, int* rBN, int* rBM) {
  const int ns = NMI * 16;
  const int t = threadIdx.x;
  const int wave = t >> 6, lane = t & 63;
  const int m = lane & 15, quad = lane >> 4;
  const int ntg = wave * 2;

  if (t < ns) {
    int gs = base + t;
    int b = gs / 300;
    int r = gs - b * 300;
    int mm = r / 10, n = r - mm * 10;
    rBN[t] = b * 10 + n;
    rBM[t] = b * 30 + mm;
  }
  __syncthreads();

  const int c8s = (t & 31) * 8;  // invariant across staging j-iterations
  const int s0 = t >> 5;

  // ---- P1+P2: hp2 = relu(relu(Ap+Ep+bp1) @ Wp2 + bp2), K-tiled ----
  {
    f32x4 acc[NMI][2];
#pragma unroll
    for (int mi = 0; mi < NMI; ++mi) {
      acc[mi][0] = (f32x4){0, 0, 0, 0};
      acc[mi][1] = (f32x4){0, 0, 0, 0};
    }
#pragma unroll 1
    for (int kh = 0; kh < 2; ++kh) {
      const int gc = kh * 256 + c8s;
      v4 b0 = *(const v4*)&bp1[gc], b1 = *(const v4*)&bp1[gc + 4];
#pragma unroll
      for (int j = 0; j < NMI; ++j) {
        int s = s0 + 16 * j;
        s8 ap = *(const s8*)&Apb[rBN[s] * 512 + gc];
        s8 ep = *(const s8*)&Epb[rBM[s] * 512 + gc];
        s8 pk;
#pragma unroll
        for (int jj = 0; jj < 4; ++jj) {
          pk[jj] = f2b(fmaxf(b2f(ap[jj]) + b2f(ep[jj]) + b0[jj], 0.f));
          pk[4 + jj] = f2b(fmaxf(b2f(ap[4 + jj]) + b2f(ep[4 + jj]) + b1[jj], 0.f));
        }
        *(s8*)&h1h[s * 264 + c8s] = pk;
      }
      __syncthreads();
      const int ktg0 = kh * 8;
      s8 bc[2], bn1[2];
#pragma unroll
      for (int i = 0; i < 2; ++i) {
        bc[i] = *(const s8*)&P2p[((ktg0 * 16 + ntg + i) * 64 + lane) * 8];
        bn1[i] = *(const s8*)&P2p[(((ktg0 + 1) * 16 + ntg + i) * 64 + lane) * 8];
      }
#pragma unroll
      for (int ktl = 0; ktl < 8; ++ktl) {
        s8 bn2[2];
        if (ktl < 6) {
#pragma unroll
          for (int i = 0; i < 2; ++i)
            bn2[i] = *(const s8*)&P2p[(((ktg0 + ktl + 2) * 16 + ntg + i) * 64 + lane) * 8];
        }
        s8 a[NMI];
#pragma unroll
        for (int mi = 0; mi < NMI; ++mi)
          a[mi] = *(const s8*)&h1h[(mi * 16 + m) * 264 + ktl * 32 + quad * 8];
#pragma unroll
        for (int i = 0; i < 2; ++i)
#pragma unroll
          for (int mi = 0; mi < NMI; ++mi)
            acc[mi][i] = __builtin_amdgcn_mfma_f32_16x16x32_bf16(a[mi], bc[i], acc[mi][i], 0, 0, 0);
        bc[0] = bn1[0]; bc[1] = bn1[1]; bn1[0] = bn2[0]; bn1[1] = bn2[1];
      }
      __syncthreads();
    }
#pragma unroll
    for (int i = 0; i < 2; ++i) {
      int col = (ntg + i) * 16 + m;
      float bb = bp2[col];
#pragma unroll
      for (int mi = 0; mi < NMI; ++mi)
#pragma unroll
        for (int r = 0; r < 4; ++r)
          h2c[(mi * 16 + quad * 4 + r) * 264 + col] =
              f2b(fmaxf(acc[mi][i][r] + bb, 0.f));
    }
  }
  __syncthreads();

  // ---- P3a: [mu|lv] = hp2 @ ZP, K=256 -> zf fp32 ----
  if (wave < 2 * NMI) {
    const int mi = wave >> 1;
#pragma unroll
    for (int iz = 0; iz < 2; ++iz) {
      const int ntz = (wave & 1) * 2 + iz;
      f32x4 accz = {0};
#pragma unroll 2
      for (int kt = 0; kt < 8; ++kt) {
        s8 a = *(const s8*)&h2c[(mi * 16 + m) * 264 + kt * 32 + quad * 8];
        s8 b = *(const s8*)&ZPp[((kt * 4 + ntz) * 64 + lane) * 8];
        accz = __builtin_amdgcn_mfma_f32_16x16x32_bf16(a, b, accz, 0, 0, 0);
      }
      const int islv = ntz >> 1;
      const int c = (ntz & 1) * 16 + m;
#pragma unroll
      for (int r = 0; r < 4; ++r)
        zf[(islv * ns + mi * 16 + quad * 4 + r) * 33 + c] = accz[r];
    }
  }
  __syncthreads();

  // ---- P3b: z = mu + eps*exp(0.5*lv) -> zb bf16 ----
  if (t < ns * 8) {
    const int row = t >> 3, l0 = (t & 7) * 4;
    const int gs = base + row;
    v4 mu = *(const v4*)&zf[row * 33 + l0];
    v4 lv = *(const v4*)&zf[(ns + row) * 33 + l0];
    v4 bm_ = *(const v4*)&bmu[l0], bl_ = *(const v4*)&blv[l0];
    v4 ev = *(const v4*)&eps[gs * 32 + l0];
#pragma unroll
    for (int j = 0; j < 4; ++j)
      zb[row * 40 + l0 + j] =
          f2b(mu[j] + bm_[j] + ev[j] * __expf(0.5f * (lv[j] + bl_[j])));
  }
  __syncthreads();  // zf fully consumed before P3c overwrites regA

  // ---- P3c+P4+P5: hg2 = relu(hg1 @ Wg2 + bg2), K-tiled with inline P4 ----
  {
    f32x4 acc[NMI][2];
#pragma unroll
    for (int mi = 0; mi < NMI; ++mi) {
      acc[mi][0] = (f32x4){0, 0, 0, 0};
      acc[mi][1] = (f32x4){0, 0, 0, 0};
    }
#pragma unroll 1
    for (int kh = 0; kh < 2; ++kh) {
      const int gc = kh * 256 + c8s;
      v4 b0 = *(const v4*)&bg1[gc], b1 = *(const v4*)&bg1[gc + 4];
#pragma unroll
      for (int j = 0; j < NMI; ++j) {
        int s = s0 + 16 * j;
        s8 ag = *(const s8*)&Agb[rBN[s] * 512 + gc];
        s8 eg = *(const s8*)&Egb[rBM[s] * 512 + gc];
        s8 pk;
#pragma unroll
        for (int jj = 0; jj < 4; ++jj) {
          pk[jj] = f2b(b2f(ag[jj]) + b2f(eg[jj]) + b0[jj]);
          pk[4 + jj] = f2b(b2f(ag[4 + jj]) + b2f(eg[4 + jj]) + b1[jj]);
        }
        *(s8*)&h1h[s * 264 + c8s] = pk;
      }
      __syncthreads();
#pragma unroll
      for (int i = 0; i < 2; ++i) {
        const int ntl = wave * 2 + i;
        s8 aG = *(const s8*)&G1p[((kh * 16 + ntl) * 64 + lane) * 8];
#pragma unroll
        for (int mi = 0; mi < NMI; ++mi) {
          s8 bz = *(const s8*)&zb[(mi * 16 + m) * 40 + quad * 8];
          f32x4 upd = {0};
          upd = __builtin_amdgcn_mfma_f32_16x16x32_bf16(aG, bz, upd, 0, 0, 0);
          short* p = &h1h[(mi * 16 + m) * 264 + ntl * 16 + quad * 4];
          s4 cur = *(s4*)p;
          s4 nw;
#pragma unroll
          for (int r = 0; r < 4; ++r)
            nw[r] = f2b(fmaxf(b2f(cur[r]) + upd[r], 0.f));
          *(s4*)p = nw;
        }
      }
      __syncthreads();
      const int ktg0 = kh * 8;
      s8 bc[2], bn1[2];
#pragma unroll
      for (int i = 0; i < 2; ++i) {
        bc[i] = *(const s8*)&G2p[((ktg0 * 16 + ntg + i) * 64 + lane) * 8];
        bn1[i] = *(const s8*)&G2p[(((ktg0 + 1) * 16 + ntg + i) * 64 + lane) * 8];
      }
#pragma unroll
      for (int ktl = 0; ktl < 8; ++ktl) {
        s8 bn2[2];
        if (ktl < 6) {
#pragma unroll
          for (int i = 0; i < 2; ++i)
            bn2[i] = *(const s8*)&G2p[(((ktg0 + ktl + 2) * 16 + ntg + i) * 64 + lane) * 8];
        }
        s8 a[NMI];
#pragma unroll
        for (int mi = 0; mi < NMI; ++mi)
          a[mi] = *(const s8*)&h1h[(mi * 16 + m) * 264 + ktl * 32 + quad * 8];
#pragma unroll
        for (int i = 0; i < 2; ++i)
#pragma unroll
          for (int mi = 0; mi < NMI; ++mi)
            acc[mi][i] = __builtin_amdgcn_mfma_f32_16x16x32_bf16(a[mi], bc[i], acc[mi][i], 0, 0, 0);
        bc[0] = bn1[0]; bc[1] = bn1[1]; bn1[0] = bn2[0]; bn1[1] = bn2[1];
      }
      __syncthreads();
    }
#pragma unroll
    for (int i = 0; i < 2; ++i) {
      int col = (ntg + i) * 16 + m;
      float bb = bg2[col];
#pragma unroll
      for (int mi = 0; mi < NMI; ++mi)
#pragma unroll
        for (int r = 0; r < 4; ++r)
          h2c[(mi * 16 + quad * 4 + r) * 264 + col] =
              f2b(fmaxf(acc[mi][i][r] + bb, 0.f));
    }
  }
  __syncthreads();

  // ---- P6: out = hg2 @ Wg3 + bg3, K=256, 240 cols ----
  {
#pragma unroll 1
    for (int i = 0; i < 2; ++i) {
      int nt = wave * 2 + i;
      if (nt >= 15) continue;
      f32x4 acc[NMI];
#pragma unroll
      for (int mi = 0; mi < NMI; ++mi) acc[mi] = (f32x4){0, 0, 0, 0};
      s8 b0 = *(const s8*)&G3p[((0 * 15 + nt) * 64 + lane) * 8];
      s8 b1 = *(const s8*)&G3p[((1 * 15 + nt) * 64 + lane) * 8];
#pragma unroll
      for (int kt = 0; kt < 8; ++kt) {
        s8 bn;
        if (kt < 6)
          bn = *(const s8*)&G3p[(((kt + 2) * 15 + nt) * 64 + lane) * 8];
#pragma unroll
        for (int mi = 0; mi < NMI; ++mi) {
          s8 a = *(const s8*)&h2c[(mi * 16 + m) * 264 + kt * 32 + quad * 8];
          acc[mi] = __builtin_amdgcn_mfma_f32_16x16x32_bf16(a, b0, acc[mi], 0, 0, 0);
        }
        b0 = b1; b1 = bn;
      }
      int col = nt * 16 + m;
      float bb = bg3[col];
#pragma unroll
      for (int mi = 0; mi < NMI; ++mi)
#pragma unroll
        for (int r = 0; r < 4; ++r) {
          int gs = base + mi * 16 + quad * 4 + r;
          out[gs * 240 + col] = acc[mi][r] + bb;
        }
    }
  }
}

__global__ __launch_bounds__(512, 4) void k_mega(
    const short* __restrict__ Apb, const short* __restrict__ Agb,
    const short* __restrict__ Epb, const short* __restrict__ Egb,
    const float* __restrict__ bp1, const float* __restrict__ bg1,
    const float* __restrict__ bp2, const float* __restrict__ bmu,
    const float* __restrict__ blv, const float* __restrict__ eps,
    const float* __restrict__ bg2, const float* __restrict__ bg3,
    const short* __restrict__ P2p, const short* __restrict__ G2p,
    const short* __restrict__ G3p, const short* __restrict__ G1p,
    const short* __restrict__ ZPp, float* __restrict__ out) {
  __shared__ __align__(16) unsigned char smem[54528];
  __shared__ int rBN[48], rBM[48];
  short* h1h = (short*)smem;             // [48][264]
  short* h2c = (short*)(smem + 25344);   // [48][264]
  short* zb = (short*)(smem + 50688);    // [48][40]
  float* zf = (float*)smem;              // overlay [2*ns][33]

  const int blk = blockIdx.x;
  if (blk < 176) {
    mega_body<3>(blk * 48, Apb, Agb, Epb, Egb, bp1, bg1, bp2, bmu, blv, eps,
                 bg2, bg3, P2p, G2p, G3p, G1p, ZPp, out, h1h, h2c, zb, zf,
                 rBN, rBM);
  } else {
    mega_body<2>(8448 + (blk - 176) * 32, Apb, Agb, Epb, Egb, bp1, bg1, bp2,
                 bmu, blv, eps, bg2, bg3, P2p, G2p, G3p, G1p, ZPp, out, h1h,
                 h2c, zb, zf, rBN, rBM);
  }
}

extern "C" void kernel_launch(void* const* d_in, const int* in_sizes, int n_in,
                              void* d_out, int out_size, void* d_ws,
                              size_t ws_size, hipStream_t stream) {
  const float* enc = (const float*)d_in[0];
  const float* etr = (const float*)d_in[1];
  const float* gtf = (const float*)d_in[2];
  const float* eps = (const float*)d_in[3];
  const int* nidx = (const int*)d_in[4];
  const float* We1 = (const float*)d_in[7];
  const float* be1 = (const float*)d_in[8];
  const float* We2 = (const float*)d_in[9];
  const float* be2 = (const float*)d_in[10];
  const float* Wp1 = (const float*)d_in[11];
  const float* bp1 = (const float*)d_in[12];
  const float* Wp2 = (const float*)d_in[13];
  const float* bp2 = (const float*)d_in[14];
  const float* Wmu = (const float*)d_in[15];
  const float* bmu = (const float*)d_in[16];
  const float* Wlv = (const float*)d_in[17];
  const float* blv = (const float*)d_in[18];
  const float* Wg1 = (const float*)d_in[19];
  const float* bg1 = (const float*)d_in[20];
  const float* Wg2 = (const float*)d_in[21];
  const float* bg2 = (const float*)d_in[22];
  const float* Wg3 = (const float*)d_in[23];
  const float* bg3 = (const float*)d_in[24];

  float* ws = (float*)d_ws;
  float* ego = ws;                  // 491,520 floats
  short* bfbase = (short*)(ws + 491520);
  short* Apb = bfbase;              // 640*512
  short* Agb = Apb + 327680;
  short* Epb = Agb + 327680;        // 1920*512
  short* Egb = Epb + 983040;
  short* pool = Egb + 983040;       // 2,060,288 shorts
  short* P2p = pool + 1703936;
  short* G2p = pool + 1835008;
  short* G3p = pool + 1966080;
  short* G1p = pool + 2027520;
  short* ZPp = pool + 2043904;

  k_pre<<<1486, 256, 0, stream>>>(Wp1, Wg1, Wp2, Wg2, Wg3, Wmu, Wlv, pool, etr,
                                  We1, be1, We2, be2, ego);
  k_condE<<<dim3(120, 2, 4), 256, 0, stream>>>(enc, gtf, nidx, ego, pool, Apb,
                                               Agb, Epb, Egb);
  k_mega<<<512, 512, 0, stream>>>(Apb, Agb, Epb, Egb, bp1, bg1, bp2, bmu, blv,
                                  eps, bg2, bg3, P2p, G2p, G3p, G1p, ZPp,
                                  (float*)d_out);
}

// Round 2
// 173.343 us; speedup vs baseline: 1.0420x; 1.0071x over previous
//
#include <hip/hip_runtime.h>
#include <hip/hip_bf16.h>

typedef float v4 __attribute__((ext_vector_type(4)));
typedef float f32x4 __attribute__((ext_vector_type(4)));
typedef short s8 __attribute__((ext_vector_type(8)));
typedef short s4 __attribute__((ext_vector_type(4)));

__device__ __forceinline__ short f2b(float x) {
  return __builtin_bit_cast(short, __float2bfloat16(x));
}
__device__ __forceinline__ float b2f(short s) {
  return __bfloat162float(__builtin_bit_cast(__hip_bfloat16, s));
}

// Dims: B=64 M=30 N=10 AGENT=256 EGO=256 LAT=32 NA=11 NP=4 PAY=1024 FUT=240

// ---------------------------------------------------------------------------
// K-pre: fused weight packing (blocks 0..1005) + ego MLP (blocks 1006..1485,
// 4 bm per block). Pool layout (short-element offsets), frags [kt][nt][lane][8]:
//   PC0 @0        Wp1 cond rows (virt K1520 pad 1536), 48kt x 32nt   786432
//   PC1 @786432   Wg1 cond rows (K1280),               40kt x 32nt   655360
//   PE0 @1441792  Wp1 ego rows 256..511 (K256),         8kt x 32nt   131072
//   PE1 @1572864  Wg1 ego rows (K256),                  8kt x 32nt   131072
//   P2p @1703936  Wp2 (512x256),                       16kt x 16nt   131072
//   G2p @1835008  Wg2,                                 16kt x 16nt   131072
//   G3p @1966080  Wg3 (256x240),                        8kt x 15nt    61440
//   G1p @2027520  Wg1 rows 1536..1567 (K=32),           1kt x 32nt    16384
//   ZPp @2043904  [Wmu|Wlv] (256x64),                   8kt x  4nt    16384
// ---------------------------------------------------------------------------
__global__ __launch_bounds__(256) void k_pre(
    const float* __restrict__ Wp1, const float* __restrict__ Wg1,
    const float* __restrict__ Wp2, const float* __restrict__ Wg2,
    const float* __restrict__ Wg3, const float* __restrict__ Wmu,
    const float* __restrict__ Wlv, short* __restrict__ pool,
    const float* __restrict__ x, const float* __restrict__ W1,
    const float* __restrict__ b1, const float* __restrict__ W2,
    const float* __restrict__ b2, float* __restrict__ ego) {
  const int t = threadIdx.x;
  if (blockIdx.x >= 1006) {
    // ---- ego MLP: 4 bm rows per block, vectorized LDS reads ----
    __shared__ __align__(16) float xls[1920];    // 4 x 480
    __shared__ float hpart[2][4][128];
    __shared__ float hbar[4][128];
    const int bm0 = (blockIdx.x - 1006) * 4;
    const float* xp = x + bm0 * 480;
#pragma unroll
    for (int i = 0; i < 2; ++i) {
      int idx = t + i * 256;  // 480 v4 items total
      if (idx < 480) *(v4*)&xls[idx * 4] = *(const v4*)&xp[idx * 4];
    }
    __syncthreads();
    {
      const int hid = t & 127, th = t >> 7;
      float w0 = W1[0 * 128 + hid], w1 = W1[1 * 128 + hid];
      float w2 = W1[2 * 128 + hid], w3 = W1[3 * 128 + hid];
      float w4 = W1[4 * 128 + hid], w5 = W1[5 * 128 + hid];
      float bb = b1[hid];
#pragma unroll 1
      for (int bm = 0; bm < 4; ++bm) {
        const float* base = &xls[bm * 480 + th * 240];
        float acc = 0.f;
#pragma unroll 4
        for (int tt = 0; tt < 40; tt += 2) {
          v4 a = *(const v4*)(base + tt * 6);
          v4 b = *(const v4*)(base + tt * 6 + 4);
          v4 c = *(const v4*)(base + tt * 6 + 8);
          float h0 = bb;
          h0 = fmaf(a[0], w0, h0); h0 = fmaf(a[1], w1, h0);
          h0 = fmaf(a[2], w2, h0); h0 = fmaf(a[3], w3, h0);
          h0 = fmaf(b[0], w4, h0); h0 = fmaf(b[1], w5, h0);
          float h1 = bb;
          h1 = fmaf(b[2], w0, h1); h1 = fmaf(b[3], w1, h1);
          h1 = fmaf(c[0], w2, h1); h1 = fmaf(c[1], w3, h1);
          h1 = fmaf(c[2], w4, h1); h1 = fmaf(c[3], w5, h1);
          acc += fmaxf(h0, 0.f) + fmaxf(h1, 0.f);
        }
        hpart[th][bm][hid] = acc;
      }
    }
    __syncthreads();
    if (t < 128) {
#pragma unroll
      for (int bm = 0; bm < 4; ++bm)
        hbar[bm][t] = (hpart[0][bm][t] + hpart[1][bm][t]) * (1.0f / 80.0f);
    }
    __syncthreads();
    {
      float acc0 = b2[t], acc1 = acc0, acc2 = acc0, acc3 = acc0;
#pragma unroll 8
      for (int j = 0; j < 128; ++j) {
        float w = W2[j * 256 + t];
        acc0 = fmaf(hbar[0][j], w, acc0);
        acc1 = fmaf(hbar[1][j], w, acc1);
        acc2 = fmaf(hbar[2][j], w, acc2);
        acc3 = fmaf(hbar[3][j], w, acc3);
      }
      ego[(bm0 + 0) * 256 + t] = acc0;
      ego[(bm0 + 1) * 256 + t] = acc1;
      ego[(bm0 + 2) * 256 + t] = acc2;
      ego[(bm0 + 3) * 256 + t] = acc3;
    }
    return;
  }
  int idx = blockIdx.x * 256 + t;
  const float* W; short* O; int NT, N, rel, mode, Kv;
  if (idx < 98304)       { W = Wp1;            O = pool;           NT = 32; N = 512; rel = idx;          mode = 0; Kv = 1520; }
  else if (idx < 180224) { W = Wg1;            O = pool + 786432;  NT = 32; N = 512; rel = idx - 98304;  mode = 0; Kv = 1280; }
  else if (idx < 196608) { W = Wp1 + 256*512;  O = pool + 1441792; NT = 32; N = 512; rel = idx - 180224; mode = 1; Kv = 256; }
  else if (idx < 212992) { W = Wg1 + 256*512;  O = pool + 1572864; NT = 32; N = 512; rel = idx - 196608; mode = 1; Kv = 256; }
  else if (idx < 229376) { W = Wp2;            O = pool + 1703936; NT = 16; N = 256; rel = idx - 212992; mode = 1; Kv = 512; }
  else if (idx < 245760) { W = Wg2;            O = pool + 1835008; NT = 16; N = 256; rel = idx - 229376; mode = 1; Kv = 512; }
  else if (idx < 253440) { W = Wg3;            O = pool + 1966080; NT = 15; N = 240; rel = idx - 245760; mode = 1; Kv = 256; }
  else if (idx < 255488) { W = Wg1 + 1536*512; O = pool + 2027520; NT = 32; N = 512; rel = idx - 253440; mode = 1; Kv = 32; }
  else if (idx < 257536) { W = Wmu;            O = pool + 2043904; NT = 4;  N = 64;  rel = idx - 255488; mode = 2; Kv = 256; }
  else return;
  int lane = rel & 63, g = rel >> 6;
  int nt = g % NT, kt = g / NT;
  int k0 = kt * 32 + (lane >> 4) * 8;
  int n = nt * 16 + (lane & 15);
  s8 pk;
#pragma unroll
  for (int j = 0; j < 8; ++j) {
    int vk = k0 + j;
    float v = 0.f;
    if (vk < Kv) {
      if (mode == 2) v = (n < 32) ? Wmu[vk * 32 + n] : Wlv[vk * 32 + (n - 32)];
      else {
        int wrow = (mode == 0 && vk >= 256) ? vk + 256 : vk;
        v = W[wrow * N + n];
      }
    }
    pk[j] = f2b(v);
  }
  *(s8*)&O[rel * 8] = pk;
}

// ---------------------------------------------------------------------------
// K-condE: merged-pair A/E GEMMs, 256 thr, col-quarter split.
// grid (120, 2, 4): grp0 tiles 0..39 (cond), grp1 tiles 0..119 (ego).
// ---------------------------------------------------------------------------
__global__ __launch_bounds__(256, 4) void k_condE(
    const float* __restrict__ enc, const float* __restrict__ gtf,
    const int* __restrict__ nidx, const float* __restrict__ ego,
    const short* __restrict__ pool, short* __restrict__ Apb,
    short* __restrict__ Agb, short* __restrict__ Epb,
    short* __restrict__ Egb) {
  __shared__ __align__(16) short xs[16 * 1560];
  const int grp = blockIdx.y, tile = blockIdx.x, quarter = blockIdx.z;
  if (grp == 0 && tile >= 40) return;
  const int row0 = tile * 16;
  const int t = threadIdx.x;
  const int wave = t >> 6, lane = t & 63;
  const int m = lane & 15, quad = lane >> 4;
  const int ntg = quarter * 8 + wave * 2;

  if (grp == 0) {
    for (int i = t; i < 3072; i += 256) {
      int s = i / 192, kk = (i - s * 192) * 8;
      int r = row0 + s;
      s8 pk;
      if (kk >= 1520) {
#pragma unroll
        for (int j = 0; j < 8; ++j) pk[j] = 0;
      } else {
        int bb = r / 10, n = r - bb * 10;
        const float* src;
        if (kk < 256) src = enc + (bb * 11 + 1 + n) * 256 + kk;
        else if (kk < 1280) {
          int jj = kk - 256; int p = jj >> 8, cc = jj & 255;
          int a = nidx[(bb * 10 + n) * 4 + p];
          src = enc + (bb * 11 + a) * 256 + cc;
        } else src = gtf + (bb * 10 + n) * 240 + (kk - 1280);
        v4 a = *(const v4*)src;
        v4 b = *(const v4*)(src + 4);
#pragma unroll
        for (int j = 0; j < 4; ++j) { pk[j] = f2b(a[j]); pk[4 + j] = f2b(b[j]); }
      }
      *(s8*)&xs[s * 1560 + kk] = pk;
    }
    __syncthreads();
    const short* PC1 = pool + 786432;
    f32x4 aP[2] = {{0}, {0}}, aG[2] = {{0}, {0}};
    s8 c0[2], c1[2];
#pragma unroll
    for (int i = 0; i < 2; ++i) {
      c0[i] = *(const s8*)&pool[((ntg + i) * 64 + lane) * 8];
      c1[i] = *(const s8*)&PC1[((ntg + i) * 64 + lane) * 8];
    }
#pragma unroll 2
    for (int kt = 0; kt < 48; ++kt) {
      s8 n0[2], n1[2];
      if (kt < 47) {
#pragma unroll
        for (int i = 0; i < 2; ++i)
          n0[i] = *(const s8*)&pool[(((kt + 1) * 32 + ntg + i) * 64 + lane) * 8];
        if (kt + 1 < 40) {
#pragma unroll
          for (int i = 0; i < 2; ++i)
            n1[i] = *(const s8*)&PC1[(((kt + 1) * 32 + ntg + i) * 64 + lane) * 8];
        }
      }
      s8 a = *(const s8*)&xs[m * 1560 + kt * 32 + quad * 8];
#pragma unroll
      for (int i = 0; i < 2; ++i)
        aP[i] = __builtin_amdgcn_mfma_f32_16x16x32_bf16(a, c0[i], aP[i], 0, 0, 0);
      if (kt < 40) {
#pragma unroll
        for (int i = 0; i < 2; ++i)
          aG[i] = __builtin_amdgcn_mfma_f32_16x16x32_bf16(a, c1[i], aG[i], 0, 0, 0);
      }
      c0[0] = n0[0]; c0[1] = n0[1]; c1[0] = n1[0]; c1[1] = n1[1];
    }
#pragma unroll
    for (int i = 0; i < 2; ++i) {
      int col = (ntg + i) * 16 + m;
#pragma unroll
      for (int r = 0; r < 4; ++r) {
        int row = row0 + quad * 4 + r;
        Apb[row * 512 + col] = f2b(aP[i][r]);
        Agb[row * 512 + col] = f2b(aG[i][r]);
      }
    }
  } else {
    for (int i = t; i < 512; i += 256) {
      int s = i >> 5, kk = (i & 31) * 8;
      const float* src = ego + (row0 + s) * 256 + kk;
      v4 a = *(const v4*)src;
      v4 b = *(const v4*)(src + 4);
      s8 pk;
#pragma unroll
      for (int j = 0; j < 4; ++j) { pk[j] = f2b(a[j]); pk[4 + j] = f2b(b[j]); }
      *(s8*)&xs[s * 1560 + kk] = pk;
    }
    __syncthreads();
    const short* PE0 = pool + 1441792;
    const short* PE1 = pool + 1572864;
    f32x4 aP[2] = {{0}, {0}}, aG[2] = {{0}, {0}};
    s8 c0[2], c1[2];
#pragma unroll
    for (int i = 0; i < 2; ++i) {
      c0[i] = *(const s8*)&PE0[((ntg + i) * 64 + lane) * 8];
      c1[i] = *(const s8*)&PE1[((ntg + i) * 64 + lane) * 8];
    }
#pragma unroll 2
    for (int kt = 0; kt < 8; ++kt) {
      s8 n0[2], n1[2];
      if (kt < 7) {
#pragma unroll
        for (int i = 0; i < 2; ++i) {
          n0[i] = *(const s8*)&PE0[(((kt + 1) * 32 + ntg + i) * 64 + lane) * 8];
          n1[i] = *(const s8*)&PE1[(((kt + 1) * 32 + ntg + i) * 64 + lane) * 8];
        }
      }
      s8 a = *(const s8*)&xs[m * 1560 + kt * 32 + quad * 8];
#pragma unroll
      for (int i = 0; i < 2; ++i) {
        aP[i] = __builtin_amdgcn_mfma_f32_16x16x32_bf16(a, c0[i], aP[i], 0, 0, 0);
        aG[i] = __builtin_amdgcn_mfma_f32_16x16x32_bf16(a, c1[i], aG[i], 0, 0, 0);
      }
      c0[0] = n0[0]; c0[1] = n0[1]; c1[0] = n1[0]; c1[1] = n1[1];
    }
#pragma unroll
    for (int i = 0; i < 2; ++i) {
      int col = (ntg + i) * 16 + m;
#pragma unroll
      for (int r = 0; r < 4; ++r) {
        int row = row0 + quad * 4 + r;
        Epb[row * 512 + col] = f2b(aP[i][r]);
        Egb[row * 512 + col] = f2b(aG[i][r]);
      }
    }
  }
}

// ---------------------------------------------------------------------------
// K-mega: mixed grid (176 x 48-sample + 336 x 32-sample = 19200), full-K
// staging (no kh halving), fused mu/lv/z phase. 9 syncthreads per block
// (was 15). LDS 79104+384 B -> 2 blocks/CU (158,976 <= 163,840):
//   h1h [48][520] bf16 (49920)  full-K hp1 / sumG+z@G1
//   h2c [48][264] bf16 (25344)  hp2, reused as hg2
//   zb  [48][40]  bf16 ( 3840)
// ---------------------------------------------------------------------------
template <int NMI>
__device__ __forceinline__ void mega_body(
    const int base,
    const short* __restrict__ Apb, const short* __restrict__ Agb,
    const short* __restrict__ Epb, const short* __restrict__ Egb,
    const float* __restrict__ bp1, const float* __restrict__ bg1,
    const float* __restrict__ bp2, const float* __restrict__ bmu,
    const float* __restrict__ blv, const float* __restrict__ eps,
    const float* __restrict__ bg2, const float* __restrict__ bg3,
    const short* __restrict__ P2p, const short* __restrict__ G2p,
    const short* __restrict__ G3p, const short* __restrict__ G1p,
    const short* __restrict__ ZPp, float* __restrict__ out,
    short* h1h, short* h2c, short* zb, int* rBN, int* rBM) {
  const int ns = NMI * 16;
  const int t = threadIdx.x;
  const int wave = t >> 6, lane = t & 63;
  const int m = lane & 15, quad = lane >> 4;
  const int ntg = wave * 2;

  if (t < ns) {
    int gs = base + t;
    int b = gs / 300;
    int r = gs - b * 300;
    int mm = r / 10, n = r - mm * 10;
    rBN[t] = b * 10 + n;
    rBM[t] = b * 30 + mm;
  }
  __syncthreads();

  const int c8 = (t & 63) * 8;  // column chunk, invariant across stage iters
  const int sb = t >> 6;        // starting row

  // ---- P1+P2: hp2 = relu(relu(Ap+Ep+bp1) @ Wp2 + bp2), full-K ----
  {
    f32x4 acc[NMI][2];
#pragma unroll
    for (int mi = 0; mi < NMI; ++mi) {
      acc[mi][0] = (f32x4){0, 0, 0, 0};
      acc[mi][1] = (f32x4){0, 0, 0, 0};
    }
    v4 b0 = *(const v4*)&bp1[c8], b1 = *(const v4*)&bp1[c8 + 4];
#pragma unroll
    for (int j = 0; j < NMI * 2; ++j) {
      int s = sb + 8 * j;
      s8 ap = *(const s8*)&Apb[rBN[s] * 512 + c8];
      s8 ep = *(const s8*)&Epb[rBM[s] * 512 + c8];
      s8 pk;
#pragma unroll
      for (int jj = 0; jj < 4; ++jj) {
        pk[jj] = f2b(fmaxf(b2f(ap[jj]) + b2f(ep[jj]) + b0[jj], 0.f));
        pk[4 + jj] = f2b(fmaxf(b2f(ap[4 + jj]) + b2f(ep[4 + jj]) + b1[jj], 0.f));
      }
      *(s8*)&h1h[s * 520 + c8] = pk;
    }
    __syncthreads();
    s8 bc[2], bn1[2];
#pragma unroll
    for (int i = 0; i < 2; ++i) {
      bc[i] = *(const s8*)&P2p[((0 * 16 + ntg + i) * 64 + lane) * 8];
      bn1[i] = *(const s8*)&P2p[((1 * 16 + ntg + i) * 64 + lane) * 8];
    }
#pragma unroll
    for (int kt = 0; kt < 16; ++kt) {
      s8 bn2[2];
      if (kt < 14) {
#pragma unroll
        for (int i = 0; i < 2; ++i)
          bn2[i] = *(const s8*)&P2p[(((kt + 2) * 16 + ntg + i) * 64 + lane) * 8];
      }
      s8 a[NMI];
#pragma unroll
      for (int mi = 0; mi < NMI; ++mi)
        a[mi] = *(const s8*)&h1h[(mi * 16 + m) * 520 + kt * 32 + quad * 8];
#pragma unroll
      for (int i = 0; i < 2; ++i)
#pragma unroll
        for (int mi = 0; mi < NMI; ++mi)
          acc[mi][i] = __builtin_amdgcn_mfma_f32_16x16x32_bf16(a[mi], bc[i], acc[mi][i], 0, 0, 0);
      bc[0] = bn1[0]; bc[1] = bn1[1]; bn1[0] = bn2[0]; bn1[1] = bn2[1];
    }
    // epilogue touches only h2c + regs: no sync needed before it
#pragma unroll
    for (int i = 0; i < 2; ++i) {
      int col = (ntg + i) * 16 + m;
      float bb = bp2[col];
#pragma unroll
      for (int mi = 0; mi < NMI; ++mi)
#pragma unroll
        for (int r = 0; r < 4; ++r)
          h2c[(mi * 16 + quad * 4 + r) * 264 + col] =
              f2b(fmaxf(acc[mi][i][r] + bb, 0.f));
    }
  }
  __syncthreads();

  // ---- P3: fused [mu|lv] GEMM + z = mu + eps*exp(0.5*lv) -> zb ----
  if (wave < 2 * NMI) {
    const int mi = wave >> 1, half = wave & 1;
    f32x4 amu = {0}, alv = {0};
#pragma unroll 2
    for (int kt = 0; kt < 8; ++kt) {
      s8 a = *(const s8*)&h2c[(mi * 16 + m) * 264 + kt * 32 + quad * 8];
      s8 bm8 = *(const s8*)&ZPp[((kt * 4 + half) * 64 + lane) * 8];
      s8 bl8 = *(const s8*)&ZPp[((kt * 4 + 2 + half) * 64 + lane) * 8];
      amu = __builtin_amdgcn_mfma_f32_16x16x32_bf16(a, bm8, amu, 0, 0, 0);
      alv = __builtin_amdgcn_mfma_f32_16x16x32_bf16(a, bl8, alv, 0, 0, 0);
    }
    const int lat = half * 16 + m;
    const float bm_ = bmu[lat], bl_ = blv[lat];
#pragma unroll
    for (int r = 0; r < 4; ++r) {
      int row = mi * 16 + quad * 4 + r;
      float ev = eps[(base + row) * 32 + lat];
      zb[row * 40 + lat] =
          f2b(amu[r] + bm_ + ev * __expf(0.5f * (alv[r] + bl_)));
    }
  }
  __syncthreads();

  // ---- P4+P5: hg2 = relu((sumG + z@G1 -> relu) @ Wg2 + bg2), full-K ----
  {
    f32x4 acc[NMI][2];
#pragma unroll
    for (int mi = 0; mi < NMI; ++mi) {
      acc[mi][0] = (f32x4){0, 0, 0, 0};
      acc[mi][1] = (f32x4){0, 0, 0, 0};
    }
    v4 g0 = *(const v4*)&bg1[c8], g1 = *(const v4*)&bg1[c8 + 4];
#pragma unroll
    for (int j = 0; j < NMI * 2; ++j) {
      int s = sb + 8 * j;
      s8 ag = *(const s8*)&Agb[rBN[s] * 512 + c8];
      s8 eg = *(const s8*)&Egb[rBM[s] * 512 + c8];
      s8 pk;
#pragma unroll
      for (int jj = 0; jj < 4; ++jj) {
        pk[jj] = f2b(b2f(ag[jj]) + b2f(eg[jj]) + g0[jj]);
        pk[4 + jj] = f2b(b2f(ag[4 + jj]) + b2f(eg[4 + jj]) + g1[jj]);
      }
      *(s8*)&h1h[s * 520 + c8] = pk;
    }
    __syncthreads();
    // inline z @ Wg1[1536:1568] update, 4 column-tiles per wave
    {
      s8 aGv[4];
#pragma unroll
      for (int i = 0; i < 4; ++i)
        aGv[i] = *(const s8*)&G1p[((wave * 4 + i) * 64 + lane) * 8];
#pragma unroll
      for (int mi = 0; mi < NMI; ++mi) {
        s8 bz = *(const s8*)&zb[(mi * 16 + m) * 40 + quad * 8];
#pragma unroll
        for (int i = 0; i < 4; ++i) {
          const int ntl = wave * 4 + i;
          f32x4 upd = {0};
          upd = __builtin_amdgcn_mfma_f32_16x16x32_bf16(aGv[i], bz, upd, 0, 0, 0);
          short* p = &h1h[(mi * 16 + m) * 520 + ntl * 16 + quad * 4];
          s4 cur = *(s4*)p;
          s4 nw;
#pragma unroll
          for (int r = 0; r < 4; ++r)
            nw[r] = f2b(fmaxf(b2f(cur[r]) + upd[r], 0.f));
          *(s4*)p = nw;
        }
      }
    }
    __syncthreads();
    s8 bc[2], bn1[2];
#pragma unroll
    for (int i = 0; i < 2; ++i) {
      bc[i] = *(const s8*)&G2p[((0 * 16 + ntg + i) * 64 + lane) * 8];
      bn1[i] = *(const s8*)&G2p[((1 * 16 + ntg + i) * 64 + lane) * 8];
    }
#pragma unroll
    for (int kt = 0; kt < 16; ++kt) {
      s8 bn2[2];
      if (kt < 14) {
#pragma unroll
        for (int i = 0; i < 2; ++i)
          bn2[i] = *(const s8*)&G2p[(((kt + 2) * 16 + ntg + i) * 64 + lane) * 8];
      }
      s8 a[NMI];
#pragma unroll
      for (int mi = 0; mi < NMI; ++mi)
        a[mi] = *(const s8*)&h1h[(mi * 16 + m) * 520 + kt * 32 + quad * 8];
#pragma unroll
      for (int i = 0; i < 2; ++i)
#pragma unroll
        for (int mi = 0; mi < NMI; ++mi)
          acc[mi][i] = __builtin_amdgcn_mfma_f32_16x16x32_bf16(a[mi], bc[i], acc[mi][i], 0, 0, 0);
      bc[0] = bn1[0]; bc[1] = bn1[1]; bn1[0] = bn2[0]; bn1[1] = bn2[1];
    }
#pragma unroll
    for (int i = 0; i < 2; ++i) {
      int col = (ntg + i) * 16 + m;
      float bb = bg2[col];
#pragma unroll
      for (int mi = 0; mi < NMI; ++mi)
#pragma unroll
        for (int r = 0; r < 4; ++r)
          h2c[(mi * 16 + quad * 4 + r) * 264 + col] =
              f2b(fmaxf(acc[mi][i][r] + bb, 0.f));
    }
  }
  __syncthreads();

  // ---- P6: out = hg2 @ Wg3 + bg3, K=256, 240 cols ----
  {
#pragma unroll 1
    for (int i = 0; i < 2; ++i) {
      int nt = wave * 2 + i;
      if (nt >= 15) continue;
      f32x4 acc[NMI];
#pragma unroll
      for (int mi = 0; mi < NMI; ++mi) acc[mi] = (f32x4){0, 0, 0, 0};
      s8 b0 = *(const s8*)&G3p[((0 * 15 + nt) * 64 + lane) * 8];
      s8 b1 = *(const s8*)&G3p[((1 * 15 + nt) * 64 + lane) * 8];
#pragma unroll
      for (int kt = 0; kt < 8; ++kt) {
        s8 bn;
        if (kt < 6)
          bn = *(const s8*)&G3p[(((kt + 2) * 15 + nt) * 64 + lane) * 8];
#pragma unroll
        for (int mi = 0; mi < NMI; ++mi) {
          s8 a = *(const s8*)&h2c[(mi * 16 + m) * 264 + kt * 32 + quad * 8];
          acc[mi] = __builtin_amdgcn_mfma_f32_16x16x32_bf16(a, b0, acc[mi], 0, 0, 0);
        }
        b0 = b1; b1 = bn;
      }
      int col = nt * 16 + m;
      float bb = bg3[col];
#pragma unroll
      for (int mi = 0; mi < NMI; ++mi)
#pragma unroll
        for (int r = 0; r < 4; ++r) {
          int gs = base + mi * 16 + quad * 4 + r;
          out[gs * 240 + col] = acc[mi][r] + bb;
        }
    }
  }
}

__global__ __launch_bounds__(512, 4) void k_mega(
    const short* __restrict__ Apb, const short* __restrict__ Agb,
    const short* __restrict__ Epb, const short* __restrict__ Egb,
    const float* __restrict__ bp1, const float* __restrict__ bg1,
    const float* __restrict__ bp2, const float* __restrict__ bmu,
    const float* __restrict__ blv, const float* __restrict__ eps,
    const float* __restrict__ bg2, const float* __restrict__ bg3,
    const short* __restrict__ P2p, const short* __restrict__ G2p,
    const short* __restrict__ G3p, const short* __restrict__ G1p,
    const short* __restrict__ ZPp, float* __restrict__ out) {
  __shared__ __align__(16) unsigned char smem[79104];
  __shared__ int rBN[48], rBM[48];
  short* h1h = (short*)smem;             // [48][520]
  short* h2c = (short*)(smem + 49920);   // [48][264]
  short* zb = (short*)(smem + 75264);    // [48][40]

  const int blk = blockIdx.x;
  if (blk < 176) {
    mega_body<3>(blk * 48, Apb, Agb, Epb, Egb, bp1, bg1, bp2, bmu, blv, eps,
                 bg2, bg3, P2p, G2p, G3p, G1p, ZPp, out, h1h, h2c, zb,
                 rBN, rBM);
  } else {
    mega_body<2>(8448 + (blk - 176) * 32, Apb, Agb, Epb, Egb, bp1, bg1, bp2,
                 bmu, blv, eps, bg2, bg3, P2p, G2p, G3p, G1p, ZPp, out, h1h,
                 h2c, zb, rBN, rBM);
  }
}

extern "C" void kernel_launch(void* const* d_in, const int* in_sizes, int n_in,
                              void* d_out, int out_size, void* d_ws,
                              size_t ws_size, hipStream_t stream) {
  const float* enc = (const float*)d_in[0];
  const float* etr = (const float*)d_in[1];
  const float* gtf = (const float*)d_in[2];
  const float* eps = (const float*)d_in[3];
  const int* nidx = (const int*)d_in[4];
  const float* We1 = (const float*)d_in[7];
  const float* be1 = (const float*)d_in[8];
  const float* We2 = (const float*)d_in[9];
  const float* be2 = (const float*)d_in[10];
  const float* Wp1 = (const float*)d_in[11];
  const float* bp1 = (const float*)d_in[12];
  const float* Wp2 = (const float*)d_in[13];
  const float* bp2 = (const float*)d_in[14];
  const float* Wmu = (const float*)d_in[15];
  const float* bmu = (const float*)d_in[16];
  const float* Wlv = (const float*)d_in[17];
  const float* blv = (const float*)d_in[18];
  const float* Wg1 = (const float*)d_in[19];
  const float* bg1 = (const float*)d_in[20];
  const float* Wg2 = (const float*)d_in[21];
  const float* bg2 = (const float*)d_in[22];
  const float* Wg3 = (const float*)d_in[23];
  const float* bg3 = (const float*)d_in[24];

  float* ws = (float*)d_ws;
  float* ego = ws;                  // 491,520 floats
  short* bfbase = (short*)(ws + 491520);
  short* Apb = bfbase;              // 640*512
  short* Agb = Apb + 327680;
  short* Epb = Agb + 327680;        // 1920*512
  short* Egb = Epb + 983040;
  short* pool = Egb + 983040;       // 2,060,288 shorts
  short* P2p = pool + 1703936;
  short* G2p = pool + 1835008;
  short* G3p = pool + 1966080;
  short* G1p = pool + 2027520;
  short* ZPp = pool + 2043904;

  k_pre<<<1486, 256, 0, stream>>>(Wp1, Wg1, Wp2, Wg2, Wg3, Wmu, Wlv, pool, etr,
                                  We1, be1, We2, be2, ego);
  k_condE<<<dim3(120, 2, 4), 256, 0, stream>>>(enc, gtf, nidx, ego, pool, Apb,
                                               Agb, Epb, Egb);
  k_mega<<<512, 512, 0, stream>>>(Apb, Agb, Epb, Egb, bp1, bg1, bp2, bmu, blv,
                                  eps, bg2, bg3, P2p, G2p, G3p, G1p, ZPp,
                                  (float*)d_out);
}

// Round 3
// 170.402 us; speedup vs baseline: 1.0599x; 1.0173x over previous
//
#include <hip/hip_runtime.h>
#include <hip/hip_bf16.h>

typedef float v4 __attribute__((ext_vector_type(4)));
typedef float f32x4 __attribute__((ext_vector_type(4)));
typedef short s8 __attribute__((ext_vector_type(8)));
typedef short s4 __attribute__((ext_vector_type(4)));

__device__ __forceinline__ short f2b(float x) {
  return __builtin_bit_cast(short, __float2bfloat16(x));
}
__device__ __forceinline__ float b2f(short s) {
  return __bfloat162float(__builtin_bit_cast(__hip_bfloat16, s));
}

// Dims: B=64 M=30 N=10 AGENT=256 EGO=256 LAT=32 NA=11 NP=4 PAY=1024 FUT=240

// ---------------------------------------------------------------------------
// K-pre: fused weight packing (blocks 0..1005) + ego MLP (blocks 1006..1485,
// 4 bm per block). Pool layout (short-element offsets), frags [kt][nt][lane][8]:
//   PC0 @0        Wp1 cond rows (virt K1520 pad 1536), 48kt x 32nt   786432
//   PC1 @786432   Wg1 cond rows (K1280),               40kt x 32nt   655360
//   PE0 @1441792  Wp1 ego rows 256..511 (K256),         8kt x 32nt   131072
//   PE1 @1572864  Wg1 ego rows (K256),                  8kt x 32nt   131072
//   P2p @1703936  Wp2 (512x256),                       16kt x 16nt   131072
//   G2p @1835008  Wg2,                                 16kt x 16nt   131072
//   G3p @1966080  Wg3 (256x240),                        8kt x 15nt    61440
//   G1p @2027520  Wg1 rows 1536..1567 (K=32),           1kt x 32nt    16384
//   ZPp @2043904  [Wmu|Wlv] (256x64),                   8kt x  4nt    16384
// ---------------------------------------------------------------------------
__global__ __launch_bounds__(256) void k_pre(
    const float* __restrict__ Wp1, const float* __restrict__ Wg1,
    const float* __restrict__ Wp2, const float* __restrict__ Wg2,
    const float* __restrict__ Wg3, const float* __restrict__ Wmu,
    const float* __restrict__ Wlv, short* __restrict__ pool,
    const float* __restrict__ x, const float* __restrict__ W1,
    const float* __restrict__ b1, const float* __restrict__ W2,
    const float* __restrict__ b2, float* __restrict__ ego) {
  const int t = threadIdx.x;
  if (blockIdx.x >= 1006) {
    // ---- ego MLP: 4 bm rows per block, vectorized LDS reads ----
    __shared__ __align__(16) float xls[1920];    // 4 x 480
    __shared__ float hpart[2][4][128];
    __shared__ float hbar[4][128];
    const int bm0 = (blockIdx.x - 1006) * 4;
    const float* xp = x + bm0 * 480;
#pragma unroll
    for (int i = 0; i < 2; ++i) {
      int idx = t + i * 256;  // 480 v4 items total
      if (idx < 480) *(v4*)&xls[idx * 4] = *(const v4*)&xp[idx * 4];
    }
    __syncthreads();
    {
      const int hid = t & 127, th = t >> 7;
      float w0 = W1[0 * 128 + hid], w1 = W1[1 * 128 + hid];
      float w2 = W1[2 * 128 + hid], w3 = W1[3 * 128 + hid];
      float w4 = W1[4 * 128 + hid], w5 = W1[5 * 128 + hid];
      float bb = b1[hid];
#pragma unroll 1
      for (int bm = 0; bm < 4; ++bm) {
        const float* base = &xls[bm * 480 + th * 240];
        float acc = 0.f;
#pragma unroll 4
        for (int tt = 0; tt < 40; tt += 2) {
          v4 a = *(const v4*)(base + tt * 6);
          v4 b = *(const v4*)(base + tt * 6 + 4);
          v4 c = *(const v4*)(base + tt * 6 + 8);
          float h0 = bb;
          h0 = fmaf(a[0], w0, h0); h0 = fmaf(a[1], w1, h0);
          h0 = fmaf(a[2], w2, h0); h0 = fmaf(a[3], w3, h0);
          h0 = fmaf(b[0], w4, h0); h0 = fmaf(b[1], w5, h0);
          float h1 = bb;
          h1 = fmaf(b[2], w0, h1); h1 = fmaf(b[3], w1, h1);
          h1 = fmaf(c[0], w2, h1); h1 = fmaf(c[1], w3, h1);
          h1 = fmaf(c[2], w4, h1); h1 = fmaf(c[3], w5, h1);
          acc += fmaxf(h0, 0.f) + fmaxf(h1, 0.f);
        }
        hpart[th][bm][hid] = acc;
      }
    }
    __syncthreads();
    if (t < 128) {
#pragma unroll
      for (int bm = 0; bm < 4; ++bm)
        hbar[bm][t] = (hpart[0][bm][t] + hpart[1][bm][t]) * (1.0f / 80.0f);
    }
    __syncthreads();
    {
      float acc0 = b2[t], acc1 = acc0, acc2 = acc0, acc3 = acc0;
#pragma unroll 8
      for (int j = 0; j < 128; ++j) {
        float w = W2[j * 256 + t];
        acc0 = fmaf(hbar[0][j], w, acc0);
        acc1 = fmaf(hbar[1][j], w, acc1);
        acc2 = fmaf(hbar[2][j], w, acc2);
        acc3 = fmaf(hbar[3][j], w, acc3);
      }
      ego[(bm0 + 0) * 256 + t] = acc0;
      ego[(bm0 + 1) * 256 + t] = acc1;
      ego[(bm0 + 2) * 256 + t] = acc2;
      ego[(bm0 + 3) * 256 + t] = acc3;
    }
    return;
  }
  int idx = blockIdx.x * 256 + t;
  const float* W; short* O; int NT, N, rel, mode, Kv;
  if (idx < 98304)       { W = Wp1;            O = pool;           NT = 32; N = 512; rel = idx;          mode = 0; Kv = 1520; }
  else if (idx < 180224) { W = Wg1;            O = pool + 786432;  NT = 32; N = 512; rel = idx - 98304;  mode = 0; Kv = 1280; }
  else if (idx < 196608) { W = Wp1 + 256*512;  O = pool + 1441792; NT = 32; N = 512; rel = idx - 180224; mode = 1; Kv = 256; }
  else if (idx < 212992) { W = Wg1 + 256*512;  O = pool + 1572864; NT = 32; N = 512; rel = idx - 196608; mode = 1; Kv = 256; }
  else if (idx < 229376) { W = Wp2;            O = pool + 1703936; NT = 16; N = 256; rel = idx - 212992; mode = 1; Kv = 512; }
  else if (idx < 245760) { W = Wg2;            O = pool + 1835008; NT = 16; N = 256; rel = idx - 229376; mode = 1; Kv = 512; }
  else if (idx < 253440) { W = Wg3;            O = pool + 1966080; NT = 15; N = 240; rel = idx - 245760; mode = 1; Kv = 256; }
  else if (idx < 255488) { W = Wg1 + 1536*512; O = pool + 2027520; NT = 32; N = 512; rel = idx - 253440; mode = 1; Kv = 32; }
  else if (idx < 257536) { W = Wmu;            O = pool + 2043904; NT = 4;  N = 64;  rel = idx - 255488; mode = 2; Kv = 256; }
  else return;
  int lane = rel & 63, g = rel >> 6;
  int nt = g % NT, kt = g / NT;
  int k0 = kt * 32 + (lane >> 4) * 8;
  int n = nt * 16 + (lane & 15);
  s8 pk;
#pragma unroll
  for (int j = 0; j < 8; ++j) {
    int vk = k0 + j;
    float v = 0.f;
    if (vk < Kv) {
      if (mode == 2) v = (n < 32) ? Wmu[vk * 32 + n] : Wlv[vk * 32 + (n - 32)];
      else {
        int wrow = (mode == 0 && vk >= 256) ? vk + 256 : vk;
        v = W[wrow * N + n];
      }
    }
    pk[j] = f2b(v);
  }
  *(s8*)&O[rel * 8] = pk;
}

// ---------------------------------------------------------------------------
// K-condE: B-fragment-reuse restructure. 100 blocks x 1024 thr (16 waves);
// each wave owns ONE nt column-tile and loops over RT row-tiles, so each
// pool B-fragment feeds RT MFMAs (was 1). Pool L2 traffic 174 MB -> 71 MB;
// grp0 x-tile staging redundancy 4x -> 1x.
//   blocks 0..39 : cond rows. rg = bx>>1 (20 groups of 32 rows, RT=2),
//                  ntg0 = (bx&1)*16. LDS xs[32][1560] = 99,840 B.
//   blocks 40..99: ego rows. e=bx-40, rg = e>>1 (30 groups of 64 rows, RT=4),
//                  ntg0 = (e&1)*16. LDS xs[64][264] (within same buffer).
// ---------------------------------------------------------------------------
__global__ __launch_bounds__(1024, 4) void k_condE(
    const float* __restrict__ enc, const float* __restrict__ gtf,
    const int* __restrict__ nidx, const float* __restrict__ ego,
    const short* __restrict__ pool, short* __restrict__ Apb,
    short* __restrict__ Agb, short* __restrict__ Epb,
    short* __restrict__ Egb) {
  __shared__ __align__(16) short xs[32 * 1560];
  const int bx = blockIdx.x;
  const int t = threadIdx.x;
  const int wave = t >> 6, lane = t & 63;
  const int m = lane & 15, quad = lane >> 4;

  if (bx < 40) {
    // ---- cond GEMM: 32 rows (RT=2), 16 nt per block ----
    const int row0 = (bx >> 1) * 32;
    const int nt = (bx & 1) * 16 + wave;
    for (int i = t; i < 6144; i += 1024) {
      int s = i / 192, kk = (i - s * 192) * 8;
      int r = row0 + s;
      s8 pk;
      if (kk >= 1520) {
#pragma unroll
        for (int j = 0; j < 8; ++j) pk[j] = 0;
      } else {
        int bb = r / 10, n = r - bb * 10;
        const float* src;
        if (kk < 256) src = enc + (bb * 11 + 1 + n) * 256 + kk;
        else if (kk < 1280) {
          int jj = kk - 256; int p = jj >> 8, cc = jj & 255;
          int a = nidx[(bb * 10 + n) * 4 + p];
          src = enc + (bb * 11 + a) * 256 + cc;
        } else src = gtf + (bb * 10 + n) * 240 + (kk - 1280);
        v4 a = *(const v4*)src;
        v4 b = *(const v4*)(src + 4);
#pragma unroll
        for (int j = 0; j < 4; ++j) { pk[j] = f2b(a[j]); pk[4 + j] = f2b(b[j]); }
      }
      *(s8*)&xs[s * 1560 + kk] = pk;
    }
    __syncthreads();
    const short* PC1 = pool + 786432;
    f32x4 aP[2] = {{0}, {0}}, aG[2] = {{0}, {0}};
    s8 c0 = *(const s8*)&pool[((0 * 32 + nt) * 64 + lane) * 8];
    s8 c1 = *(const s8*)&PC1[((0 * 32 + nt) * 64 + lane) * 8];
#pragma unroll 2
    for (int kt = 0; kt < 48; ++kt) {
      s8 n0, n1;
      if (kt < 47) {
        n0 = *(const s8*)&pool[(((kt + 1) * 32 + nt) * 64 + lane) * 8];
        if (kt + 1 < 40)
          n1 = *(const s8*)&PC1[(((kt + 1) * 32 + nt) * 64 + lane) * 8];
      }
      s8 a0 = *(const s8*)&xs[(0 * 16 + m) * 1560 + kt * 32 + quad * 8];
      s8 a1 = *(const s8*)&xs[(1 * 16 + m) * 1560 + kt * 32 + quad * 8];
      aP[0] = __builtin_amdgcn_mfma_f32_16x16x32_bf16(a0, c0, aP[0], 0, 0, 0);
      aP[1] = __builtin_amdgcn_mfma_f32_16x16x32_bf16(a1, c0, aP[1], 0, 0, 0);
      if (kt < 40) {
        aG[0] = __builtin_amdgcn_mfma_f32_16x16x32_bf16(a0, c1, aG[0], 0, 0, 0);
        aG[1] = __builtin_amdgcn_mfma_f32_16x16x32_bf16(a1, c1, aG[1], 0, 0, 0);
      }
      c0 = n0; c1 = n1;
    }
    const int col = nt * 16 + m;
#pragma unroll
    for (int rt = 0; rt < 2; ++rt) {
#pragma unroll
      for (int r = 0; r < 4; ++r) {
        int row = row0 + rt * 16 + quad * 4 + r;
        Apb[row * 512 + col] = f2b(aP[rt][r]);
        Agb[row * 512 + col] = f2b(aG[rt][r]);
      }
    }
  } else {
    // ---- ego GEMM: 64 rows (RT=4), 16 nt per block ----
    const int e = bx - 40;
    const int row0 = (e >> 1) * 64;
    const int nt = (e & 1) * 16 + wave;
    for (int i = t; i < 2048; i += 1024) {
      int s = i >> 5, kk = (i & 31) * 8;
      const float* src = ego + (row0 + s) * 256 + kk;
      v4 a = *(const v4*)src;
      v4 b = *(const v4*)(src + 4);
      s8 pk;
#pragma unroll
      for (int j = 0; j < 4; ++j) { pk[j] = f2b(a[j]); pk[4 + j] = f2b(b[j]); }
      *(s8*)&xs[s * 264 + kk] = pk;
    }
    __syncthreads();
    const short* PE0 = pool + 1441792;
    const short* PE1 = pool + 1572864;
    f32x4 aP[4] = {{0}, {0}, {0}, {0}}, aG[4] = {{0}, {0}, {0}, {0}};
    s8 c0 = *(const s8*)&PE0[((0 * 32 + nt) * 64 + lane) * 8];
    s8 c1 = *(const s8*)&PE1[((0 * 32 + nt) * 64 + lane) * 8];
#pragma unroll
    for (int kt = 0; kt < 8; ++kt) {
      s8 n0, n1;
      if (kt < 7) {
        n0 = *(const s8*)&PE0[(((kt + 1) * 32 + nt) * 64 + lane) * 8];
        n1 = *(const s8*)&PE1[(((kt + 1) * 32 + nt) * 64 + lane) * 8];
      }
#pragma unroll
      for (int rt = 0; rt < 4; ++rt) {
        s8 a = *(const s8*)&xs[(rt * 16 + m) * 264 + kt * 32 + quad * 8];
        aP[rt] = __builtin_amdgcn_mfma_f32_16x16x32_bf16(a, c0, aP[rt], 0, 0, 0);
        aG[rt] = __builtin_amdgcn_mfma_f32_16x16x32_bf16(a, c1, aG[rt], 0, 0, 0);
      }
      c0 = n0; c1 = n1;
    }
    const int col = nt * 16 + m;
#pragma unroll
    for (int rt = 0; rt < 4; ++rt) {
#pragma unroll
      for (int r = 0; r < 4; ++r) {
        int row = row0 + rt * 16 + quad * 4 + r;
        Epb[row * 512 + col] = f2b(aP[rt][r]);
        Egb[row * 512 + col] = f2b(aG[rt][r]);
      }
    }
  }
}

// ---------------------------------------------------------------------------
// K-mega: mixed grid (176 x 48-sample + 336 x 32-sample = 19200), full-K
// staging, fused mu/lv/z phase. LDS 79104+384 B -> 2 blocks/CU:
//   h1h [48][520] bf16 (49920)  full-K hp1 / sumG+z@G1
//   h2c [48][264] bf16 (25344)  hp2, reused as hg2
//   zb  [48][40]  bf16 ( 3840)
// ---------------------------------------------------------------------------
template <int NMI>
__device__ __forceinline__ void mega_body(
    const int base,
    const short* __restrict__ Apb, const short* __restrict__ Agb,
    const short* __restrict__ Epb, const short* __restrict__ Egb,
    const float* __restrict__ bp1, const float* __restrict__ bg1,
    const float* __restrict__ bp2, const float* __restrict__ bmu,
    const float* __restrict__ blv, const float* __restrict__ eps,
    const float* __restrict__ bg2, const float* __restrict__ bg3,
    const short* __restrict__ P2p, const short* __restrict__ G2p,
    const short* __restrict__ G3p, const short* __restrict__ G1p,
    const short* __restrict__ ZPp, float* __restrict__ out,
    short* h1h, short* h2c, short* zb, int* rBN, int* rBM) {
  const int ns = NMI * 16;
  const int t = threadIdx.x;
  const int wave = t >> 6, lane = t & 63;
  const int m = lane & 15, quad = lane >> 4;
  const int ntg = wave * 2;

  if (t < ns) {
    int gs = base + t;
    int b = gs / 300;
    int r = gs - b * 300;
    int mm = r / 10, n = r - mm * 10;
    rBN[t] = b * 10 + n;
    rBM[t] = b * 30 + mm;
  }
  __syncthreads();

  const int c8 = (t & 63) * 8;  // column chunk, invariant across stage iters
  const int sb = t >> 6;        // starting row

  // ---- P1+P2: hp2 = relu(relu(Ap+Ep+bp1) @ Wp2 + bp2), full-K ----
  {
    f32x4 acc[NMI][2];
#pragma unroll
    for (int mi = 0; mi < NMI; ++mi) {
      acc[mi][0] = (f32x4){0, 0, 0, 0};
      acc[mi][1] = (f32x4){0, 0, 0, 0};
    }
    v4 b0 = *(const v4*)&bp1[c8], b1 = *(const v4*)&bp1[c8 + 4];
#pragma unroll
    for (int j = 0; j < NMI * 2; ++j) {
      int s = sb + 8 * j;
      s8 ap = *(const s8*)&Apb[rBN[s] * 512 + c8];
      s8 ep = *(const s8*)&Epb[rBM[s] * 512 + c8];
      s8 pk;
#pragma unroll
      for (int jj = 0; jj < 4; ++jj) {
        pk[jj] = f2b(fmaxf(b2f(ap[jj]) + b2f(ep[jj]) + b0[jj], 0.f));
        pk[4 + jj] = f2b(fmaxf(b2f(ap[4 + jj]) + b2f(ep[4 + jj]) + b1[jj], 0.f));
      }
      *(s8*)&h1h[s * 520 + c8] = pk;
    }
    __syncthreads();
    s8 bc[2], bn1[2];
#pragma unroll
    for (int i = 0; i < 2; ++i) {
      bc[i] = *(const s8*)&P2p[((0 * 16 + ntg + i) * 64 + lane) * 8];
      bn1[i] = *(const s8*)&P2p[((1 * 16 + ntg + i) * 64 + lane) * 8];
    }
#pragma unroll
    for (int kt = 0; kt < 16; ++kt) {
      s8 bn2[2];
      if (kt < 14) {
#pragma unroll
        for (int i = 0; i < 2; ++i)
          bn2[i] = *(const s8*)&P2p[(((kt + 2) * 16 + ntg + i) * 64 + lane) * 8];
      }
      s8 a[NMI];
#pragma unroll
      for (int mi = 0; mi < NMI; ++mi)
        a[mi] = *(const s8*)&h1h[(mi * 16 + m) * 520 + kt * 32 + quad * 8];
#pragma unroll
      for (int i = 0; i < 2; ++i)
#pragma unroll
        for (int mi = 0; mi < NMI; ++mi)
          acc[mi][i] = __builtin_amdgcn_mfma_f32_16x16x32_bf16(a[mi], bc[i], acc[mi][i], 0, 0, 0);
      bc[0] = bn1[0]; bc[1] = bn1[1]; bn1[0] = bn2[0]; bn1[1] = bn2[1];
    }
    // epilogue touches only h2c + regs: no sync needed before it
#pragma unroll
    for (int i = 0; i < 2; ++i) {
      int col = (ntg + i) * 16 + m;
      float bb = bp2[col];
#pragma unroll
      for (int mi = 0; mi < NMI; ++mi)
#pragma unroll
        for (int r = 0; r < 4; ++r)
          h2c[(mi * 16 + quad * 4 + r) * 264 + col] =
              f2b(fmaxf(acc[mi][i][r] + bb, 0.f));
    }
  }
  __syncthreads();

  // ---- P3: fused [mu|lv] GEMM + z = mu + eps*exp(0.5*lv) -> zb ----
  if (wave < 2 * NMI) {
    const int mi = wave >> 1, half = wave & 1;
    f32x4 amu = {0}, alv = {0};
#pragma unroll 2
    for (int kt = 0; kt < 8; ++kt) {
      s8 a = *(const s8*)&h2c[(mi * 16 + m) * 264 + kt * 32 + quad * 8];
      s8 bm8 = *(const s8*)&ZPp[((kt * 4 + half) * 64 + lane) * 8];
      s8 bl8 = *(const s8*)&ZPp[((kt * 4 + 2 + half) * 64 + lane) * 8];
      amu = __builtin_amdgcn_mfma_f32_16x16x32_bf16(a, bm8, amu, 0, 0, 0);
      alv = __builtin_amdgcn_mfma_f32_16x16x32_bf16(a, bl8, alv, 0, 0, 0);
    }
    const int lat = half * 16 + m;
    const float bm_ = bmu[lat], bl_ = blv[lat];
#pragma unroll
    for (int r = 0; r < 4; ++r) {
      int row = mi * 16 + quad * 4 + r;
      float ev = eps[(base + row) * 32 + lat];
      zb[row * 40 + lat] =
          f2b(amu[r] + bm_ + ev * __expf(0.5f * (alv[r] + bl_)));
    }
  }
  __syncthreads();

  // ---- P4+P5: hg2 = relu((sumG + z@G1 -> relu) @ Wg2 + bg2), full-K ----
  {
    f32x4 acc[NMI][2];
#pragma unroll
    for (int mi = 0; mi < NMI; ++mi) {
      acc[mi][0] = (f32x4){0, 0, 0, 0};
      acc[mi][1] = (f32x4){0, 0, 0, 0};
    }
    v4 g0 = *(const v4*)&bg1[c8], g1 = *(const v4*)&bg1[c8 + 4];
#pragma unroll
    for (int j = 0; j < NMI * 2; ++j) {
      int s = sb + 8 * j;
      s8 ag = *(const s8*)&Agb[rBN[s] * 512 + c8];
      s8 eg = *(const s8*)&Egb[rBM[s] * 512 + c8];
      s8 pk;
#pragma unroll
      for (int jj = 0; jj < 4; ++jj) {
        pk[jj] = f2b(b2f(ag[jj]) + b2f(eg[jj]) + g0[jj]);
        pk[4 + jj] = f2b(b2f(ag[4 + jj]) + b2f(eg[4 + jj]) + g1[jj]);
      }
      *(s8*)&h1h[s * 520 + c8] = pk;
    }
    __syncthreads();
    // inline z @ Wg1[1536:1568] update, 4 column-tiles per wave
    {
      s8 aGv[4];
#pragma unroll
      for (int i = 0; i < 4; ++i)
        aGv[i] = *(const s8*)&G1p[((wave * 4 + i) * 64 + lane) * 8];
#pragma unroll
      for (int mi = 0; mi < NMI; ++mi) {
        s8 bz = *(const s8*)&zb[(mi * 16 + m) * 40 + quad * 8];
#pragma unroll
        for (int i = 0; i < 4; ++i) {
          const int ntl = wave * 4 + i;
          f32x4 upd = {0};
          upd = __builtin_amdgcn_mfma_f32_16x16x32_bf16(aGv[i], bz, upd, 0, 0, 0);
          short* p = &h1h[(mi * 16 + m) * 520 + ntl * 16 + quad * 4];
          s4 cur = *(s4*)p;
          s4 nw;
#pragma unroll
          for (int r = 0; r < 4; ++r)
            nw[r] = f2b(fmaxf(b2f(cur[r]) + upd[r], 0.f));
          *(s4*)p = nw;
        }
      }
    }
    __syncthreads();
    s8 bc[2], bn1[2];
#pragma unroll
    for (int i = 0; i < 2; ++i) {
      bc[i] = *(const s8*)&G2p[((0 * 16 + ntg + i) * 64 + lane) * 8];
      bn1[i] = *(const s8*)&G2p[((1 * 16 + ntg + i) * 64 + lane) * 8];
    }
#pragma unroll
    for (int kt = 0; kt < 16; ++kt) {
      s8 bn2[2];
      if (kt < 14) {
#pragma unroll
        for (int i = 0; i < 2; ++i)
          bn2[i] = *(const s8*)&G2p[(((kt + 2) * 16 + ntg + i) * 64 + lane) * 8];
      }
      s8 a[NMI];
#pragma unroll
      for (int mi = 0; mi < NMI; ++mi)
        a[mi] = *(const s8*)&h1h[(mi * 16 + m) * 520 + kt * 32 + quad * 8];
#pragma unroll
      for (int i = 0; i < 2; ++i)
#pragma unroll
        for (int mi = 0; mi < NMI; ++mi)
          acc[mi][i] = __builtin_amdgcn_mfma_f32_16x16x32_bf16(a[mi], bc[i], acc[mi][i], 0, 0, 0);
      bc[0] = bn1[0]; bc[1] = bn1[1]; bn1[0] = bn2[0]; bn1[1] = bn2[1];
    }
#pragma unroll
    for (int i = 0; i < 2; ++i) {
      int col = (ntg + i) * 16 + m;
      float bb = bg2[col];
#pragma unroll
      for (int mi = 0; mi < NMI; ++mi)
#pragma unroll
        for (int r = 0; r < 4; ++r)
          h2c[(mi * 16 + quad * 4 + r) * 264 + col] =
              f2b(fmaxf(acc[mi][i][r] + bb, 0.f));
    }
  }
  __syncthreads();

  // ---- P6: out = hg2 @ Wg3 + bg3, K=256, 240 cols ----
  {
#pragma unroll 1
    for (int i = 0; i < 2; ++i) {
      int nt = wave * 2 + i;
      if (nt >= 15) continue;
      f32x4 acc[NMI];
#pragma unroll
      for (int mi = 0; mi < NMI; ++mi) acc[mi] = (f32x4){0, 0, 0, 0};
      s8 b0 = *(const s8*)&G3p[((0 * 15 + nt) * 64 + lane) * 8];
      s8 b1 = *(const s8*)&G3p[((1 * 15 + nt) * 64 + lane) * 8];
#pragma unroll
      for (int kt = 0; kt < 8; ++kt) {
        s8 bn;
        if (kt < 6)
          bn = *(const s8*)&G3p[(((kt + 2) * 15 + nt) * 64 + lane) * 8];
#pragma unroll
        for (int mi = 0; mi < NMI; ++mi) {
          s8 a = *(const s8*)&h2c[(mi * 16 + m) * 264 + kt * 32 + quad * 8];
          acc[mi] = __builtin_amdgcn_mfma_f32_16x16x32_bf16(a, b0, acc[mi], 0, 0, 0);
        }
        b0 = b1; b1 = bn;
      }
      int col = nt * 16 + m;
      float bb = bg3[col];
#pragma unroll
      for (int mi = 0; mi < NMI; ++mi)
#pragma unroll
        for (int r = 0; r < 4; ++r) {
          int gs = base + mi * 16 + quad * 4 + r;
          out[gs * 240 + col] = acc[mi][r] + bb;
        }
    }
  }
}

__global__ __launch_bounds__(512, 4) void k_mega(
    const short* __restrict__ Apb, const short* __restrict__ Agb,
    const short* __restrict__ Epb, const short* __restrict__ Egb,
    const float* __restrict__ bp1, const float* __restrict__ bg1,
    const float* __restrict__ bp2, const float* __restrict__ bmu,
    const float* __restrict__ blv, const float* __restrict__ eps,
    const float* __restrict__ bg2, const float* __restrict__ bg3,
    const short* __restrict__ P2p, const short* __restrict__ G2p,
    const short* __restrict__ G3p, const short* __restrict__ G1p,
    const short* __restrict__ ZPp, float* __restrict__ out) {
  __shared__ __align__(16) unsigned char smem[79104];
  __shared__ int rBN[48], rBM[48];
  short* h1h = (short*)smem;             // [48][520]
  short* h2c = (short*)(smem + 49920);   // [48][264]
  short* zb = (short*)(smem + 75264);    // [48][40]

  const int blk = blockIdx.x;
  if (blk < 176) {
    mega_body<3>(blk * 48, Apb, Agb, Epb, Egb, bp1, bg1, bp2, bmu, blv, eps,
                 bg2, bg3, P2p, G2p, G3p, G1p, ZPp, out, h1h, h2c, zb,
                 rBN, rBM);
  } else {
    mega_body<2>(8448 + (blk - 176) * 32, Apb, Agb, Epb, Egb, bp1, bg1, bp2,
                 bmu, blv, eps, bg2, bg3, P2p, G2p, G3p, G1p, ZPp, out, h1h,
                 h2c, zb, rBN, rBM);
  }
}

extern "C" void kernel_launch(void* const* d_in, const int* in_sizes, int n_in,
                              void* d_out, int out_size, void* d_ws,
                              size_t ws_size, hipStream_t stream) {
  const float* enc = (const float*)d_in[0];
  const float* etr = (const float*)d_in[1];
  const float* gtf = (const float*)d_in[2];
  const float* eps = (const float*)d_in[3];
  const int* nidx = (const int*)d_in[4];
  const float* We1 = (const float*)d_in[7];
  const float* be1 = (const float*)d_in[8];
  const float* We2 = (const float*)d_in[9];
  const float* be2 = (const float*)d_in[10];
  const float* Wp1 = (const float*)d_in[11];
  const float* bp1 = (const float*)d_in[12];
  const float* Wp2 = (const float*)d_in[13];
  const float* bp2 = (const float*)d_in[14];
  const float* Wmu = (const float*)d_in[15];
  const float* bmu = (const float*)d_in[16];
  const float* Wlv = (const float*)d_in[17];
  const float* blv = (const float*)d_in[18];
  const float* Wg1 = (const float*)d_in[19];
  const float* bg1 = (const float*)d_in[20];
  const float* Wg2 = (const float*)d_in[21];
  const float* bg2 = (const float*)d_in[22];
  const float* Wg3 = (const float*)d_in[23];
  const float* bg3 = (const float*)d_in[24];

  float* ws = (float*)d_ws;
  float* ego = ws;                  // 491,520 floats
  short* bfbase = (short*)(ws + 491520);
  short* Apb = bfbase;              // 640*512
  short* Agb = Apb + 327680;
  short* Epb = Agb + 327680;        // 1920*512
  short* Egb = Epb + 983040;
  short* pool = Egb + 983040;       // 2,060,288 shorts
  short* P2p = pool + 1703936;
  short* G2p = pool + 1835008;
  short* G3p = pool + 1966080;
  short* G1p = pool + 2027520;
  short* ZPp = pool + 2043904;

  k_pre<<<1486, 256, 0, stream>>>(Wp1, Wg1, Wp2, Wg2, Wg3, Wmu, Wlv, pool, etr,
                                  We1, be1, We2, be2, ego);
  k_condE<<<100, 1024, 0, stream>>>(enc, gtf, nidx, ego, pool, Apb,
                                    Agb, Epb, Egb);
  k_mega<<<512, 512, 0, stream>>>(Apb, Agb, Epb, Egb, bp1, bg1, bp2, bmu, blv,
                                  eps, bg2, bg3, P2p, G2p, G3p, G1p, ZPp,
                                  (float*)d_out);
}